// Round 4
// baseline (397.528 us; speedup 1.0000x reference)
//
#include <hip/hip_runtime.h>
#include <hip/hip_bf16.h>
#include <math.h>

#define NH   16
#define NKV  4
#define HD   64
#define B_   2
#define T_   2048
#define C_   1024
#define QKVN 1536   // fused q(1024) | k(256) | v(256)

typedef __attribute__((ext_vector_type(8))) short short8;
typedef __attribute__((ext_vector_type(4))) float v4f;

__device__ inline ushort f2bf(float f) {
    union { float f; uint32_t u; } v; v.f = f;
    uint32_t r = v.u + 0x7fffu + ((v.u >> 16) & 1u);
    return (ushort)(r >> 16);
}
__device__ inline float bf2f(ushort u) {
    union { uint32_t u; float f; } v; v.u = ((uint32_t)u) << 16;
    return v.f;
}

// async global->LDS, 16B per lane; LDS dest must be wave-uniform base
__device__ inline void async16(const void* g, void* l) {
    __builtin_amdgcn_global_load_lds(
        (const __attribute__((address_space(1))) unsigned int*)g,
        (__attribute__((address_space(3))) unsigned int*)l, 16, 0, 0);
}

// ---------------- fp32 -> bf16 straight convert ---------------------------
__global__ __launch_bounds__(256) void f32_to_bf16(
    const float* __restrict__ in, ushort* __restrict__ out, int n)
{
    int i = (blockIdx.x * 256 + threadIdx.x) * 4;
    if (i >= n) return;
    float4 v = *(const float4*)(in + i);
    ushort4 o; o.x = f2bf(v.x); o.y = f2bf(v.y); o.z = f2bf(v.z); o.w = f2bf(v.w);
    *(ushort4*)(out + i) = o;
}

// ---------------- transpose + convert: W[1024,N] f32 -> WT[N][1024] bf16 ---
__global__ __launch_bounds__(256) void transpose_f32_bf16(
    const float* __restrict__ W, ushort* __restrict__ WT, int N)
{
    __shared__ float tile[64][65];
    const int tid = threadIdx.x;
    const int k0 = blockIdx.y * 64, n0 = blockIdx.x * 64;
    #pragma unroll
    for (int it = 0; it < 4; ++it) {
        int r = (tid >> 4) + it * 16;
        int c = (tid & 15) * 4;
        float4 v = *(const float4*)(W + (size_t)(k0 + r) * N + n0 + c);
        tile[r][c] = v.x; tile[r][c + 1] = v.y; tile[r][c + 2] = v.z; tile[r][c + 3] = v.w;
    }
    __syncthreads();
    #pragma unroll
    for (int it = 0; it < 4; ++it) {
        int r = (tid >> 4) + it * 16;     // output row (= n)
        int c = (tid & 15) * 4;           // output col (= k)
        ushort4 o;
        o.x = f2bf(tile[c + 0][r]); o.y = f2bf(tile[c + 1][r]);
        o.z = f2bf(tile[c + 2][r]); o.w = f2bf(tile[c + 3][r]);
        *(ushort4*)(WT + (size_t)(n0 + r) * C_ + k0 + c) = o;
    }
}

// ---- transpose v-section of qkv -> vT[(b*256 + dv)][T] bf16 ---------------
// in: qkv row stride 1536, v at col 1280. out row stride 2048.
__global__ __launch_bounds__(256) void transpose_v_bf16(
    const ushort* __restrict__ qkv, ushort* __restrict__ vT)
{
    __shared__ ushort tile[64][65];
    const int tid = threadIdx.x;
    const int t0 = blockIdx.x * 64;       // time block
    const int d0 = blockIdx.y * 64;       // v-feature block (0..255)
    const int b  = blockIdx.z;
    #pragma unroll
    for (int it = 0; it < 4; ++it) {
        int r = (tid >> 4) + it * 16;     // t offset
        int c = (tid & 15) * 4;           // d offset
        ushort4 v = *(const ushort4*)(qkv + (size_t)(b * T_ + t0 + r) * QKVN + 1280 + d0 + c);
        tile[r][c] = v.x; tile[r][c + 1] = v.y; tile[r][c + 2] = v.z; tile[r][c + 3] = v.w;
    }
    __syncthreads();
    #pragma unroll
    for (int it = 0; it < 4; ++it) {
        int r = (tid >> 4) + it * 16;     // d offset (output row)
        int c = (tid & 15) * 4;           // t offset
        ushort4 o;
        o.x = tile[c + 0][r]; o.y = tile[c + 1][r];
        o.z = tile[c + 2][r]; o.w = tile[c + 3][r];
        *(ushort4*)(vT + (size_t)(b * 256 + d0 + r) * T_ + t0 + c) = o;
    }
}

// ---------------- bf16 MFMA GEMM: C[M,N] = A[M,K] @ Bt[N,K]^T --------------
template <bool BF16OUT>
__global__ __launch_bounds__(256) void gemm_bf16bt(
    const ushort* __restrict__ A, const ushort* __restrict__ Bt,
    void* __restrict__ Cout, int M, int N, int K)
{
    __shared__ __align__(16) short As[128 * 32];
    __shared__ __align__(16) short Bs[128 * 32];

    const int tid  = threadIdx.x;
    const int lane = tid & 63;
    const int wid  = tid >> 6;
    const int l16  = lane & 15;
    const int quad = lane >> 4;
    const int wm   = wid >> 1, wn = wid & 1;
    const int m0   = blockIdx.y * 128;
    const int n0   = blockIdx.x * 128;

    v4f acc[4][4];
    #pragma unroll
    for (int i = 0; i < 4; ++i)
        #pragma unroll
        for (int j = 0; j < 4; ++j) acc[i][j] = (v4f){0.f, 0.f, 0.f, 0.f};

    for (int k0 = 0; k0 < K; k0 += 32) {
        __syncthreads();
        {
            const ushort* ag = A  + (size_t)(m0 + wid * 32 + (lane >> 2)) * K + k0 + (lane & 3) * 8;
            async16(ag,                  &As[(wid * 32) * 32]);
            async16(ag + (size_t)16 * K, &As[(wid * 32 + 16) * 32]);
            const ushort* bg = Bt + (size_t)(n0 + wid * 32 + (lane >> 2)) * K + k0 + (lane & 3) * 8;
            async16(bg,                  &Bs[(wid * 32) * 32]);
            async16(bg + (size_t)16 * K, &Bs[(wid * 32 + 16) * 32]);
        }
        __syncthreads();

        short8 af[4], bf[4];
        #pragma unroll
        for (int t = 0; t < 4; ++t) {
            af[t] = *(const short8*)&As[(wm * 64 + t * 16 + l16) * 32 + quad * 8];
            bf[t] = *(const short8*)&Bs[(wn * 64 + t * 16 + l16) * 32 + quad * 8];
        }
        #pragma unroll
        for (int i = 0; i < 4; ++i)
            #pragma unroll
            for (int j = 0; j < 4; ++j)
                acc[i][j] = __builtin_amdgcn_mfma_f32_16x16x32_bf16(af[i], bf[j], acc[i][j], 0, 0, 0);
    }

    #pragma unroll
    for (int i = 0; i < 4; ++i) {
        #pragma unroll
        for (int r = 0; r < 4; ++r) {
            const int row = m0 + wm * 64 + i * 16 + quad * 4 + r;
            #pragma unroll
            for (int j = 0; j < 4; ++j) {
                const int col = n0 + wn * 64 + j * 16 + l16;
                if (BF16OUT)
                    ((ushort*)Cout)[(size_t)row * N + col] = f2bf(acc[i][j][r]);
                else
                    ((float*)Cout)[(size_t)row * N + col] = acc[i][j][r];
            }
        }
    }
}

// ---------------- RoPE in-place on bf16 qkv buffer (row stride QKVN) ------
__global__ __launch_bounds__(256) void rope_bf16(
    ushort* __restrict__ p, const float* __restrict__ cs,
    const float* __restrict__ sn, int nh, int total)
{
    int i = blockIdx.x * 256 + threadIdx.x;
    if (i >= total) return;
    int d   = i & 31;
    int hh  = (i >> 5) % nh;
    int row = i / (32 * nh);
    int t   = row % T_;
    size_t base = (size_t)row * QKVN + hh * HD + d;
    float x1 = bf2f(p[base]), x2 = bf2f(p[base + 32]);
    float c = cs[t * 32 + d], s = sn[t * 32 + d];
    p[base]      = f2bf(x1 * c - x2 * s);
    p[base + 32] = f2bf(x2 * c + x1 * s);
}

// ---------------- MFMA flash attention, no-LDS-staging --------------------
// qkv: [B*T,1536] bf16 (rope applied). vT: [(b*256+dv)][T] bf16.
// y: [B*T,1024] bf16. K and V MFMA B-fragments loaded straight from
// global (16B dwordx4, 64B-coalesced, L1/L2-resident); no barriers.
#define LSTR 72
__global__ __launch_bounds__(256) void attn_mfma(
    const ushort* __restrict__ qkv, const ushort* __restrict__ vT,
    ushort* __restrict__ y)
{
    __shared__ __align__(16) short Ps[4][16][LSTR];

    const int tid  = threadIdx.x;
    const int wid  = tid >> 6;
    const int ln   = tid & 63;
    const int l16  = ln & 15;
    const int quad = ln >> 4;

    const int tpb = T_ / 64;
    const int blk = blockIdx.x;
    const int b   = blk / (NH * tpb);
    const int rem = blk % (NH * tpb);
    const int h   = rem / tpb;
    const int tb  = (tpb - 1) - (rem % tpb);     // heavy blocks first
    const int q0  = tb * 64;
    const int kvh = h >> 2;

    const ushort* kbase = qkv + (size_t)(b * T_) * QKVN + 1024 + kvh * HD;  // row stride QKVN
    const ushort* vtb   = vT + (size_t)(b * 256 + kvh * HD) * T_;           // row stride T_

    short8 qf[2];
    {
        const ushort* qrow = qkv + (size_t)(b * T_ + q0 + wid * 16 + l16) * QKVN + h * HD;
        qf[0] = *(const short8*)(qrow + quad * 8);
        qf[1] = *(const short8*)(qrow + 32 + quad * 8);
    }

    v4f oacc[4];
    float m[4], l[4];
    #pragma unroll
    for (int t = 0; t < 4; ++t) oacc[t] = (v4f){0.f, 0.f, 0.f, 0.f};
    #pragma unroll
    for (int r = 0; r < 4; ++r) { m[r] = -1e30f; l[r] = 0.f; }

    const int nch = q0 / 64 + 1;
    for (int c = 0; c < nch; ++c) {
        const int key0 = c * 64;

        // ---- S = Q @ K^T, K fragments direct from global ----
        v4f st[4];
        #pragma unroll
        for (int t = 0; t < 4; ++t) {
            const ushort* krow = kbase + (size_t)(key0 + t * 16 + l16) * QKVN;
            short8 b0 = *(const short8*)(krow + quad * 8);
            short8 b1 = *(const short8*)(krow + 32 + quad * 8);
            v4f s = (v4f){0.f, 0.f, 0.f, 0.f};
            s = __builtin_amdgcn_mfma_f32_16x16x32_bf16(qf[0], b0, s, 0, 0, 0);
            s = __builtin_amdgcn_mfma_f32_16x16x32_bf16(qf[1], b1, s, 0, 0, 0);
            st[t] = s;
        }

        // ---- online softmax (C layout: row=quad*4+r, col=t*16+l16) ----
        #pragma unroll
        for (int r = 0; r < 4; ++r) {
            const int rowg = q0 + wid * 16 + quad * 4 + r;
            float sv[4];
            #pragma unroll
            for (int t = 0; t < 4; ++t) {
                float s = st[t][r] * 0.125f;
                int kg = key0 + t * 16 + l16;
                sv[t] = (kg <= rowg) ? s : -1e30f;
            }
            float mx = fmaxf(fmaxf(sv[0], sv[1]), fmaxf(sv[2], sv[3]));
            mx = fmaxf(mx, __shfl_xor(mx, 8, 64));
            mx = fmaxf(mx, __shfl_xor(mx, 4, 64));
            mx = fmaxf(mx, __shfl_xor(mx, 2, 64));
            mx = fmaxf(mx, __shfl_xor(mx, 1, 64));
            float mnew  = fmaxf(m[r], mx);
            float alpha = __expf(m[r] - mnew);
            m[r] = mnew;
            float sum = 0.f;
            float pv[4];
            #pragma unroll
            for (int t = 0; t < 4; ++t) {
                pv[t] = __expf(sv[t] - mnew);
                sum += pv[t];
            }
            sum += __shfl_xor(sum, 8, 64);
            sum += __shfl_xor(sum, 4, 64);
            sum += __shfl_xor(sum, 2, 64);
            sum += __shfl_xor(sum, 1, 64);
            l[r] = l[r] * alpha + sum;
            #pragma unroll
            for (int t = 0; t < 4; ++t) {
                oacc[t][r] *= alpha;
                Ps[wid][quad * 4 + r][t * 16 + l16] = (short)f2bf(pv[t]);
            }
        }

        // wave-private P region: only this wave's ds ops need draining
        asm volatile("s_waitcnt lgkmcnt(0)" ::: "memory");

        short8 pa0 = *(const short8*)&Ps[wid][l16][quad * 8];
        short8 pa1 = *(const short8*)&Ps[wid][l16][32 + quad * 8];

        // ---- O += P @ V, V fragments direct from global vT ----
        #pragma unroll
        for (int t = 0; t < 4; ++t) {
            const ushort* vrow = vtb + (size_t)(t * 16 + l16) * T_ + key0;
            short8 v0 = *(const short8*)(vrow + quad * 8);
            short8 v1 = *(const short8*)(vrow + 32 + quad * 8);
            oacc[t] = __builtin_amdgcn_mfma_f32_16x16x32_bf16(pa0, v0, oacc[t], 0, 0, 0);
            oacc[t] = __builtin_amdgcn_mfma_f32_16x16x32_bf16(pa1, v1, oacc[t], 0, 0, 0);
        }
    }

    #pragma unroll
    for (int r = 0; r < 4; ++r) {
        const int rowg = q0 + wid * 16 + quad * 4 + r;
        float inv = 1.0f / l[r];
        ushort* yrow = y + (size_t)(b * T_ + rowg) * (NH * HD) + h * HD;
        #pragma unroll
        for (int t = 0; t < 4; ++t)
            yrow[t * 16 + l16] = f2bf(oacc[t][r] * inv);
    }
}

// ---------------- launcher ----------------
extern "C" void kernel_launch(void* const* d_in, const int* in_sizes, int n_in,
                              void* d_out, int out_size, void* d_ws, size_t ws_size,
                              hipStream_t stream)
{
    const float* x    = (const float*)d_in[0];
    const float* cosT = (const float*)d_in[1];
    const float* sinT = (const float*)d_in[2];
    const float* Wq   = (const float*)d_in[3];
    const float* Wk   = (const float*)d_in[4];
    const float* Wv   = (const float*)d_in[5];
    const float* Wo   = (const float*)d_in[6];
    float* out = (float*)d_out;

    const int M = B_ * T_;  // 4096
    ushort* xb     = (ushort*)d_ws;                       // 4096*1024
    ushort* qkv    = xb  + (size_t)M * C_;                // 4096*1536
    ushort* yb     = qkv + (size_t)M * QKVN;              // 4096*1024
    ushort* WqkvT  = yb  + (size_t)M * C_;                // 1536*1024
    ushort* WoT    = WqkvT + (size_t)QKVN * C_;           // 1024*1024
    ushort* vTbuf  = WoT + (size_t)C_ * C_;               // 2*256*2048

    dim3 blk(256);
    // converts + weight transposes
    f32_to_bf16<<<(M * C_ / 4) / 256, blk, 0, stream>>>(x, xb, M * C_);
    transpose_f32_bf16<<<dim3(16, 16), blk, 0, stream>>>(Wq, WqkvT, 1024);
    transpose_f32_bf16<<<dim3(4,  16), blk, 0, stream>>>(Wk, WqkvT + (size_t)1024 * C_, 256);
    transpose_f32_bf16<<<dim3(4,  16), blk, 0, stream>>>(Wv, WqkvT + (size_t)1280 * C_, 256);
    transpose_f32_bf16<<<dim3(16, 16), blk, 0, stream>>>(Wo, WoT, 1024);
    // fused QKV projection (bf16 out)
    gemm_bf16bt<true><<<dim3(QKVN / 128, M / 128), blk, 0, stream>>>(xb, WqkvT, qkv, M, QKVN, C_);
    // RoPE on q and k sections
    rope_bf16<<<(M * NH  * 32) / 256, blk, 0, stream>>>(qkv,        cosT, sinT, NH,  M * NH  * 32);
    rope_bf16<<<(M * NKV * 32) / 256, blk, 0, stream>>>(qkv + 1024, cosT, sinT, NKV, M * NKV * 32);
    // v -> vT global transpose
    transpose_v_bf16<<<dim3(T_ / 64, 4, B_), blk, 0, stream>>>(qkv, vTbuf);
    // attention (no LDS staging, no barriers)
    attn_mfma<<<B_ * NH * (T_ / 64), blk, 0, stream>>>(qkv, vTbuf, yb);
    // output projection (fp32 out)
    gemm_bf16bt<false><<<dim3(C_ / 128, M / 128), blk, 0, stream>>>(yb, WoT, out, M, C_, C_);
}

// Round 5
// 280.191 us; speedup vs baseline: 1.4188x; 1.4188x over previous
//
#include <hip/hip_runtime.h>
#include <hip/hip_bf16.h>
#include <math.h>

#define NH   16
#define NKV  4
#define HD   64
#define B_   2
#define T_   2048
#define C_   1024
#define QKVN 1536   // fused q(1024) | k(256) | v(256)

typedef __attribute__((ext_vector_type(8))) short short8;
typedef __attribute__((ext_vector_type(4))) float v4f;

__device__ inline ushort f2bf(float f) {
    union { float f; uint32_t u; } v; v.f = f;
    uint32_t r = v.u + 0x7fffu + ((v.u >> 16) & 1u);
    return (ushort)(r >> 16);
}
__device__ inline float bf2f(ushort u) {
    union { uint32_t u; float f; } v; v.u = ((uint32_t)u) << 16;
    return v.f;
}

// async global->LDS, 16B per lane; LDS dest wave-uniform base + lane*16
__device__ inline void async16(const void* g, void* l) {
    __builtin_amdgcn_global_load_lds(
        (const __attribute__((address_space(1))) unsigned int*)g,
        (__attribute__((address_space(3))) unsigned int*)l, 16, 0, 0);
}

// ---------------- fp32 -> bf16 straight convert ---------------------------
__global__ __launch_bounds__(256) void f32_to_bf16(
    const float* __restrict__ in, ushort* __restrict__ out, int n)
{
    int i = (blockIdx.x * 256 + threadIdx.x) * 4;
    if (i >= n) return;
    float4 v = *(const float4*)(in + i);
    ushort4 o; o.x = f2bf(v.x); o.y = f2bf(v.y); o.z = f2bf(v.z); o.w = f2bf(v.w);
    *(ushort4*)(out + i) = o;
}

// ---------------- transpose + convert: W[1024,N] f32 -> WT[N][1024] bf16 ---
__global__ __launch_bounds__(256) void transpose_f32_bf16(
    const float* __restrict__ W, ushort* __restrict__ WT, int N)
{
    __shared__ float tile[64][65];
    const int tid = threadIdx.x;
    const int k0 = blockIdx.y * 64, n0 = blockIdx.x * 64;
    #pragma unroll
    for (int it = 0; it < 4; ++it) {
        int r = (tid >> 4) + it * 16;
        int c = (tid & 15) * 4;
        float4 v = *(const float4*)(W + (size_t)(k0 + r) * N + n0 + c);
        tile[r][c] = v.x; tile[r][c + 1] = v.y; tile[r][c + 2] = v.z; tile[r][c + 3] = v.w;
    }
    __syncthreads();
    #pragma unroll
    for (int it = 0; it < 4; ++it) {
        int r = (tid >> 4) + it * 16;     // output row (= n)
        int c = (tid & 15) * 4;           // output col (= k)
        ushort4 o;
        o.x = f2bf(tile[c + 0][r]); o.y = f2bf(tile[c + 1][r]);
        o.z = f2bf(tile[c + 2][r]); o.w = f2bf(tile[c + 3][r]);
        *(ushort4*)(WT + (size_t)(n0 + r) * C_ + k0 + c) = o;
    }
}

// ---- transpose v-section of qkv -> vT[(b*256 + dv)][T] bf16 ---------------
__global__ __launch_bounds__(256) void transpose_v_bf16(
    const ushort* __restrict__ qkv, ushort* __restrict__ vT)
{
    __shared__ ushort tile[64][65];
    const int tid = threadIdx.x;
    const int t0 = blockIdx.x * 64;
    const int d0 = blockIdx.y * 64;
    const int b  = blockIdx.z;
    #pragma unroll
    for (int it = 0; it < 4; ++it) {
        int r = (tid >> 4) + it * 16;
        int c = (tid & 15) * 4;
        ushort4 v = *(const ushort4*)(qkv + (size_t)(b * T_ + t0 + r) * QKVN + 1280 + d0 + c);
        tile[r][c] = v.x; tile[r][c + 1] = v.y; tile[r][c + 2] = v.z; tile[r][c + 3] = v.w;
    }
    __syncthreads();
    #pragma unroll
    for (int it = 0; it < 4; ++it) {
        int r = (tid >> 4) + it * 16;
        int c = (tid & 15) * 4;
        ushort4 o;
        o.x = tile[c + 0][r]; o.y = tile[c + 1][r];
        o.z = tile[c + 2][r]; o.w = tile[c + 3][r];
        *(ushort4*)(vT + (size_t)(b * 256 + d0 + r) * T_ + t0 + c) = o;
    }
}

// ---------------- bf16 MFMA GEMM: C[M,N] = A[M,K] @ Bt[N,K]^T --------------
// Optional fused RoPE epilogue (QKV gemm): wave's 64-col tile = one head;
// rotate (d, d+32) pairs on fp32 accumulators iff col0 < 1280.
template <bool BF16OUT, bool ROPE>
__global__ __launch_bounds__(256) void gemm_bf16bt(
    const ushort* __restrict__ A, const ushort* __restrict__ Bt,
    void* __restrict__ Cout, const float* __restrict__ cs,
    const float* __restrict__ sn, int M, int N, int K)
{
    __shared__ __align__(16) short As[128 * 32];
    __shared__ __align__(16) short Bs[128 * 32];

    const int tid  = threadIdx.x;
    const int lane = tid & 63;
    const int wid  = tid >> 6;
    const int l16  = lane & 15;
    const int quad = lane >> 4;
    const int wm   = wid >> 1, wn = wid & 1;
    const int m0   = blockIdx.y * 128;
    const int n0   = blockIdx.x * 128;

    v4f acc[4][4];
    #pragma unroll
    for (int i = 0; i < 4; ++i)
        #pragma unroll
        for (int j = 0; j < 4; ++j) acc[i][j] = (v4f){0.f, 0.f, 0.f, 0.f};

    for (int k0 = 0; k0 < K; k0 += 32) {
        __syncthreads();
        {
            const ushort* ag = A  + (size_t)(m0 + wid * 32 + (lane >> 2)) * K + k0 + (lane & 3) * 8;
            async16(ag,                  &As[(wid * 32) * 32]);
            async16(ag + (size_t)16 * K, &As[(wid * 32 + 16) * 32]);
            const ushort* bg = Bt + (size_t)(n0 + wid * 32 + (lane >> 2)) * K + k0 + (lane & 3) * 8;
            async16(bg,                  &Bs[(wid * 32) * 32]);
            async16(bg + (size_t)16 * K, &Bs[(wid * 32 + 16) * 32]);
        }
        __syncthreads();

        short8 af[4], bf[4];
        #pragma unroll
        for (int t = 0; t < 4; ++t) {
            af[t] = *(const short8*)&As[(wm * 64 + t * 16 + l16) * 32 + quad * 8];
            bf[t] = *(const short8*)&Bs[(wn * 64 + t * 16 + l16) * 32 + quad * 8];
        }
        #pragma unroll
        for (int i = 0; i < 4; ++i)
            #pragma unroll
            for (int j = 0; j < 4; ++j)
                acc[i][j] = __builtin_amdgcn_mfma_f32_16x16x32_bf16(af[i], bf[j], acc[i][j], 0, 0, 0);
    }

    const int col0 = n0 + wn * 64;
    if (ROPE && col0 < 1280) {
        #pragma unroll
        for (int i = 0; i < 4; ++i) {
            #pragma unroll
            for (int r = 0; r < 4; ++r) {
                const int row = m0 + wm * 64 + i * 16 + quad * 4 + r;
                const int t = row & (T_ - 1);
                #pragma unroll
                for (int j = 0; j < 2; ++j) {
                    const int d = j * 16 + l16;
                    float cv = cs[t * 32 + d], sv = sn[t * 32 + d];
                    float x1 = acc[i][j][r], x2 = acc[i][j + 2][r];
                    acc[i][j][r]     = x1 * cv - x2 * sv;
                    acc[i][j + 2][r] = x2 * cv + x1 * sv;
                }
            }
        }
    }

    #pragma unroll
    for (int i = 0; i < 4; ++i) {
        #pragma unroll
        for (int r = 0; r < 4; ++r) {
            const int row = m0 + wm * 64 + i * 16 + quad * 4 + r;
            #pragma unroll
            for (int j = 0; j < 4; ++j) {
                const int col = n0 + wn * 64 + j * 16 + l16;
                if (BF16OUT)
                    ((ushort*)Cout)[(size_t)row * N + col] = f2bf(acc[i][j][r]);
                else
                    ((float*)Cout)[(size_t)row * N + col] = acc[i][j][r];
            }
        }
    }
}

// ---------------- MFMA flash attention, async dbuf staging ----------------
// qkv: [B*T,1536] bf16 (rope already applied by gemm). vT: [(b*256+dv)][T].
// y: [B*T,1024] bf16. K/V staged via global_load_lds into double-buffered
// LDS with XOR-swizzled source addressing (rows 128B contiguous; slot s of
// row rr holds global 8-short block s ^ (rr&7) -> b128 frag reads hit all
// 32 banks). One __syncthreads per chunk; its vmcnt(0) drains the DMA
// issued LAST iteration, so prefetch overlaps compute.
__global__ __launch_bounds__(256) void attn_mfma(
    const ushort* __restrict__ qkv, const ushort* __restrict__ vT,
    ushort* __restrict__ y)
{
    __shared__ __align__(16) short Ks[2][64 * 64];
    __shared__ __align__(16) short Vs[2][64 * 64];
    __shared__ __align__(16) short Ps[4][16][72];

    const int tid  = threadIdx.x;
    const int wid  = tid >> 6;
    const int ln   = tid & 63;
    const int l16  = ln & 15;
    const int quad = ln >> 4;

    const int tpb = T_ / 64;
    const int blk = blockIdx.x;
    const int b   = blk / (NH * tpb);
    const int rem = blk % (NH * tpb);
    const int h   = rem / tpb;
    const int tb  = (tpb - 1) - (rem % tpb);     // heavy blocks first
    const int q0  = tb * 64;
    const int kvh = h >> 2;

    const ushort* kbase = qkv + (size_t)(b * T_) * QKVN + 1024 + kvh * HD;
    const ushort* vtb   = vT + (size_t)(b * 256 + kvh * HD) * T_;

    // staging geometry: wave stages rows r0..r0+15 of each 64x64 tile
    const int r0   = wid * 16;
    const int srow = ln >> 3;                     // 0..7 (row within 8-group)
    const int sblk = ((ln & 7) ^ srow) * 8;       // swizzled global col (shorts)

    short8 qf[2];
    {
        const ushort* qrow = qkv + (size_t)(b * T_ + q0 + wid * 16 + l16) * QKVN + h * HD;
        qf[0] = *(const short8*)(qrow + quad * 8);
        qf[1] = *(const short8*)(qrow + 32 + quad * 8);
    }

    v4f oacc[4];
    float m[4], l[4];
    #pragma unroll
    for (int t = 0; t < 4; ++t) oacc[t] = (v4f){0.f, 0.f, 0.f, 0.f};
    #pragma unroll
    for (int r = 0; r < 4; ++r) { m[r] = -1e30f; l[r] = 0.f; }

    const int nch = q0 / 64 + 1;

    // prologue: stage chunk 0 into buf 0
    {
        const ushort* kg = kbase + (size_t)(r0 + srow) * QKVN + sblk;
        async16(kg,                    &Ks[0][r0 * 64]);
        async16(kg + (size_t)8 * QKVN, &Ks[0][(r0 + 8) * 64]);
        const ushort* vg = vtb + (size_t)(r0 + srow) * T_ + sblk;
        async16(vg,                    &Vs[0][r0 * 64]);
        async16(vg + (size_t)8 * T_,   &Vs[0][(r0 + 8) * 64]);
    }

    for (int c = 0; c < nch; ++c) {
        const int key0 = c * 64;
        __syncthreads();   // vmcnt(0) drains my chunk-c DMA; barrier = all staged
        if (c + 1 < nch) {
            const int nb = (c + 1) & 1;
            const int nk = key0 + 64;
            const ushort* kg = kbase + (size_t)(nk + r0 + srow) * QKVN + sblk;
            async16(kg,                    &Ks[nb][r0 * 64]);
            async16(kg + (size_t)8 * QKVN, &Ks[nb][(r0 + 8) * 64]);
            const ushort* vg = vtb + (size_t)(r0 + srow) * T_ + nk + sblk;
            async16(vg,                    &Vs[nb][r0 * 64]);
            async16(vg + (size_t)8 * T_,   &Vs[nb][(r0 + 8) * 64]);
        }
        const short* Kb = Ks[c & 1];
        const short* Vb = Vs[c & 1];
        const int sl0 = (quad ^ (l16 & 7)) * 8;   // slot of global blocks 0..3
        const int sl1 = sl0 ^ 32;                 // slot of blocks 4..7 (^4)*8

        // ---- S = Q @ K^T ----
        v4f st[4];
        #pragma unroll
        for (int t = 0; t < 4; ++t) {
            short8 b0 = *(const short8*)&Kb[(t * 16 + l16) * 64 + sl0];
            short8 b1 = *(const short8*)&Kb[(t * 16 + l16) * 64 + sl1];
            v4f s = (v4f){0.f, 0.f, 0.f, 0.f};
            s = __builtin_amdgcn_mfma_f32_16x16x32_bf16(qf[0], b0, s, 0, 0, 0);
            s = __builtin_amdgcn_mfma_f32_16x16x32_bf16(qf[1], b1, s, 0, 0, 0);
            st[t] = s;
        }

        // ---- online softmax (C layout: row=quad*4+r, col=t*16+l16) ----
        #pragma unroll
        for (int r = 0; r < 4; ++r) {
            const int rowg = q0 + wid * 16 + quad * 4 + r;
            float sv[4];
            #pragma unroll
            for (int t = 0; t < 4; ++t) {
                float s = st[t][r] * 0.125f;
                int kg = key0 + t * 16 + l16;
                sv[t] = (kg <= rowg) ? s : -1e30f;
            }
            float mx = fmaxf(fmaxf(sv[0], sv[1]), fmaxf(sv[2], sv[3]));
            mx = fmaxf(mx, __shfl_xor(mx, 8, 64));
            mx = fmaxf(mx, __shfl_xor(mx, 4, 64));
            mx = fmaxf(mx, __shfl_xor(mx, 2, 64));
            mx = fmaxf(mx, __shfl_xor(mx, 1, 64));
            float mnew  = fmaxf(m[r], mx);
            float alpha = __expf(m[r] - mnew);
            m[r] = mnew;
            float sum = 0.f;
            float pv[4];
            #pragma unroll
            for (int t = 0; t < 4; ++t) {
                pv[t] = __expf(sv[t] - mnew);
                sum += pv[t];
            }
            sum += __shfl_xor(sum, 8, 64);
            sum += __shfl_xor(sum, 4, 64);
            sum += __shfl_xor(sum, 2, 64);
            sum += __shfl_xor(sum, 1, 64);
            l[r] = l[r] * alpha + sum;
            #pragma unroll
            for (int t = 0; t < 4; ++t) {
                oacc[t][r] *= alpha;
                Ps[wid][quad * 4 + r][t * 16 + l16] = (short)f2bf(pv[t]);
            }
        }

        // wave-private P region: only this wave's ds ops need draining
        asm volatile("s_waitcnt lgkmcnt(0)" ::: "memory");

        short8 pa0 = *(const short8*)&Ps[wid][l16][quad * 8];
        short8 pa1 = *(const short8*)&Ps[wid][l16][32 + quad * 8];

        // ---- O += P @ V ----
        #pragma unroll
        for (int t = 0; t < 4; ++t) {
            short8 v0 = *(const short8*)&Vb[(t * 16 + l16) * 64 + sl0];
            short8 v1 = *(const short8*)&Vb[(t * 16 + l16) * 64 + sl1];
            oacc[t] = __builtin_amdgcn_mfma_f32_16x16x32_bf16(pa0, v0, oacc[t], 0, 0, 0);
            oacc[t] = __builtin_amdgcn_mfma_f32_16x16x32_bf16(pa1, v1, oacc[t], 0, 0, 0);
        }
    }

    #pragma unroll
    for (int r = 0; r < 4; ++r) {
        const int rowg = q0 + wid * 16 + quad * 4 + r;
        float inv = 1.0f / l[r];
        ushort* yrow = y + (size_t)(b * T_ + rowg) * (NH * HD) + h * HD;
        #pragma unroll
        for (int t = 0; t < 4; ++t)
            yrow[t * 16 + l16] = f2bf(oacc[t][r] * inv);
    }
}

// ---------------- launcher ----------------
extern "C" void kernel_launch(void* const* d_in, const int* in_sizes, int n_in,
                              void* d_out, int out_size, void* d_ws, size_t ws_size,
                              hipStream_t stream)
{
    const float* x    = (const float*)d_in[0];
    const float* cosT = (const float*)d_in[1];
    const float* sinT = (const float*)d_in[2];
    const float* Wq   = (const float*)d_in[3];
    const float* Wk   = (const float*)d_in[4];
    const float* Wv   = (const float*)d_in[5];
    const float* Wo   = (const float*)d_in[6];
    float* out = (float*)d_out;

    const int M = B_ * T_;  // 4096
    ushort* xb     = (ushort*)d_ws;                       // 4096*1024
    ushort* qkv    = xb  + (size_t)M * C_;                // 4096*1536
    ushort* yb     = qkv + (size_t)M * QKVN;              // 4096*1024
    ushort* WqkvT  = yb  + (size_t)M * C_;                // 1536*1024
    ushort* WoT    = WqkvT + (size_t)QKVN * C_;           // 1024*1024
    ushort* vTbuf  = WoT + (size_t)C_ * C_;               // 2*256*2048

    dim3 blk(256);
    // converts + weight transposes
    f32_to_bf16<<<(M * C_ / 4) / 256, blk, 0, stream>>>(x, xb, M * C_);
    transpose_f32_bf16<<<dim3(16, 16), blk, 0, stream>>>(Wq, WqkvT, 1024);
    transpose_f32_bf16<<<dim3(4,  16), blk, 0, stream>>>(Wk, WqkvT + (size_t)1024 * C_, 256);
    transpose_f32_bf16<<<dim3(4,  16), blk, 0, stream>>>(Wv, WqkvT + (size_t)1280 * C_, 256);
    transpose_f32_bf16<<<dim3(16, 16), blk, 0, stream>>>(Wo, WoT, 1024);
    // fused QKV projection with RoPE epilogue (bf16 out)
    gemm_bf16bt<true, true><<<dim3(QKVN / 128, M / 128), blk, 0, stream>>>(
        xb, WqkvT, qkv, cosT, sinT, M, QKVN, C_);
    // v -> vT global transpose
    transpose_v_bf16<<<dim3(T_ / 64, 4, B_), blk, 0, stream>>>(qkv, vTbuf);
    // attention (async dbuf staging)
    attn_mfma<<<B_ * NH * (T_ / 64), blk, 0, stream>>>(qkv, vTbuf, yb);
    // output projection (fp32 out)
    gemm_bf16bt<false, false><<<dim3(C_ / 128, M / 128), blk, 0, stream>>>(
        yb, WoT, out, nullptr, nullptr, M, C_, C_);
}

// Round 6
// 263.257 us; speedup vs baseline: 1.5100x; 1.0643x over previous
//
#include <hip/hip_runtime.h>
#include <hip/hip_bf16.h>
#include <math.h>

#define NH   16
#define NKV  4
#define HD   64
#define B_   2
#define T_   2048
#define C_   1024
#define QKVN 1536   // fused q(1024) | k(256) | v(256)

typedef __attribute__((ext_vector_type(8))) short short8;
typedef __attribute__((ext_vector_type(4))) float v4f;

__device__ inline ushort f2bf(float f) {
    union { float f; uint32_t u; } v; v.f = f;
    uint32_t r = v.u + 0x7fffu + ((v.u >> 16) & 1u);
    return (ushort)(r >> 16);
}

// async global->LDS, 16B per lane; LDS dest wave-uniform base + lane*16
__device__ inline void async16(const void* g, void* l) {
    __builtin_amdgcn_global_load_lds(
        (const __attribute__((address_space(1))) unsigned int*)g,
        (__attribute__((address_space(3))) unsigned int*)l, 16, 0, 0);
}

// ---------------- prep: x f32->bf16 convert + 4 weight transposes ----------
// blocks 0..639: transpose 64x64 tiles of {Wq,Wk,Wv,Wo} -> WT bf16 [N][1024]
// blocks 640..4735: convert x (4096x1024 f32) -> xb bf16
__global__ __launch_bounds__(256) void prep(
    const float* __restrict__ x,
    const float* __restrict__ Wq, const float* __restrict__ Wk,
    const float* __restrict__ Wv, const float* __restrict__ Wo,
    ushort* __restrict__ xb, ushort* __restrict__ WqkvT, ushort* __restrict__ WoT)
{
    const int bx = blockIdx.x;
    const int tid = threadIdx.x;
    if (bx < 640) {
        __shared__ float tile[64][65];
        const int cb = bx >> 4;          // 0..39 column-block
        const int kb = bx & 15;          // k-block
        const float* src; ushort* dst; int N, nb;
        if (cb < 16)      { src = Wq; dst = WqkvT;                    N = 1024; nb = cb; }
        else if (cb < 20) { src = Wk; dst = WqkvT + (size_t)1024 * C_; N = 256; nb = cb - 16; }
        else if (cb < 24) { src = Wv; dst = WqkvT + (size_t)1280 * C_; N = 256; nb = cb - 20; }
        else              { src = Wo; dst = WoT;                      N = 1024; nb = cb - 24; }
        const int k0 = kb * 64, n0 = nb * 64;
        #pragma unroll
        for (int it = 0; it < 4; ++it) {
            int r = (tid >> 4) + it * 16;
            int c = (tid & 15) * 4;
            float4 v = *(const float4*)(src + (size_t)(k0 + r) * N + n0 + c);
            tile[r][c] = v.x; tile[r][c + 1] = v.y; tile[r][c + 2] = v.z; tile[r][c + 3] = v.w;
        }
        __syncthreads();
        #pragma unroll
        for (int it = 0; it < 4; ++it) {
            int r = (tid >> 4) + it * 16;
            int c = (tid & 15) * 4;
            ushort4 o;
            o.x = f2bf(tile[c + 0][r]); o.y = f2bf(tile[c + 1][r]);
            o.z = f2bf(tile[c + 2][r]); o.w = f2bf(tile[c + 3][r]);
            *(ushort4*)(dst + (size_t)(n0 + r) * C_ + k0 + c) = o;
        }
    } else {
        int i = ((bx - 640) * 256 + tid) * 4;   // covers 4096*1024 exactly
        float4 v = *(const float4*)(x + i);
        ushort4 o; o.x = f2bf(v.x); o.y = f2bf(v.y); o.z = f2bf(v.z); o.w = f2bf(v.w);
        *(ushort4*)(xb + i) = o;
    }
}

// ---- transpose v-section of qkv -> vT[(b*256 + dv)][T] bf16 ---------------
__global__ __launch_bounds__(256) void transpose_v_bf16(
    const ushort* __restrict__ qkv, ushort* __restrict__ vT)
{
    __shared__ ushort tile[64][65];
    const int tid = threadIdx.x;
    const int t0 = blockIdx.x * 64;
    const int d0 = blockIdx.y * 64;
    const int b  = blockIdx.z;
    #pragma unroll
    for (int it = 0; it < 4; ++it) {
        int r = (tid >> 4) + it * 16;
        int c = (tid & 15) * 4;
        ushort4 v = *(const ushort4*)(qkv + (size_t)(b * T_ + t0 + r) * QKVN + 1280 + d0 + c);
        tile[r][c] = v.x; tile[r][c + 1] = v.y; tile[r][c + 2] = v.z; tile[r][c + 3] = v.w;
    }
    __syncthreads();
    #pragma unroll
    for (int it = 0; it < 4; ++it) {
        int r = (tid >> 4) + it * 16;
        int c = (tid & 15) * 4;
        ushort4 o;
        o.x = tile[c + 0][r]; o.y = tile[c + 1][r];
        o.z = tile[c + 2][r]; o.w = tile[c + 3][r];
        *(ushort4*)(vT + (size_t)(b * 256 + d0 + r) * T_ + t0 + c) = o;
    }
}

// ---------------- bf16 MFMA GEMM: C[M,N] = A[M,K] @ Bt[N,K]^T --------------
// 128(M)x64(N) tile, BK=32, 4 waves stacked along M (wave: 32m x 64n).
// ROPE epilogue (QKV gemm): the 64-col tile = one head; rotate (d,d+32) on
// fp32 accs iff n0<1280; fold attention's 1/8 scale into q (n0<1024).
template <bool BF16OUT, bool ROPE>
__global__ __launch_bounds__(256) void gemm_bf16bt(
    const ushort* __restrict__ A, const ushort* __restrict__ Bt,
    void* __restrict__ Cout, const float* __restrict__ cs,
    const float* __restrict__ sn, int M, int N, int K)
{
    __shared__ __align__(16) short As[128 * 32];
    __shared__ __align__(16) short Bs[64 * 32];

    const int tid  = threadIdx.x;
    const int lane = tid & 63;
    const int wid  = tid >> 6;
    const int l16  = lane & 15;
    const int quad = lane >> 4;
    const int m0   = blockIdx.y * 128;
    const int n0   = blockIdx.x * 64;

    v4f acc[2][4];
    #pragma unroll
    for (int i = 0; i < 2; ++i)
        #pragma unroll
        for (int j = 0; j < 4; ++j) acc[i][j] = (v4f){0.f, 0.f, 0.f, 0.f};

    for (int k0 = 0; k0 < K; k0 += 32) {
        __syncthreads();
        {
            const ushort* ag = A + (size_t)(m0 + wid * 32 + (lane >> 2)) * K + k0 + (lane & 3) * 8;
            async16(ag,                  &As[(wid * 32) * 32]);
            async16(ag + (size_t)16 * K, &As[(wid * 32 + 16) * 32]);
            const ushort* bg = Bt + (size_t)(n0 + wid * 16 + (lane >> 2)) * K + k0 + (lane & 3) * 8;
            async16(bg, &Bs[(wid * 16) * 32]);
        }
        __syncthreads();

        short8 af[2], bf[4];
        #pragma unroll
        for (int i = 0; i < 2; ++i)
            af[i] = *(const short8*)&As[(wid * 32 + i * 16 + l16) * 32 + quad * 8];
        #pragma unroll
        for (int j = 0; j < 4; ++j)
            bf[j] = *(const short8*)&Bs[(j * 16 + l16) * 32 + quad * 8];
        #pragma unroll
        for (int i = 0; i < 2; ++i)
            #pragma unroll
            for (int j = 0; j < 4; ++j)
                acc[i][j] = __builtin_amdgcn_mfma_f32_16x16x32_bf16(af[i], bf[j], acc[i][j], 0, 0, 0);
    }

    if (ROPE && n0 < 1280) {
        const float qs = (n0 < 1024) ? 0.125f : 1.0f;   // fold attn scale into q
        #pragma unroll
        for (int i = 0; i < 2; ++i) {
            #pragma unroll
            for (int r = 0; r < 4; ++r) {
                const int row = m0 + wid * 32 + i * 16 + quad * 4 + r;
                const int t = row & (T_ - 1);
                #pragma unroll
                for (int j = 0; j < 2; ++j) {
                    const int d = j * 16 + l16;
                    float cv = cs[t * 32 + d] * qs, sv = sn[t * 32 + d] * qs;
                    float x1 = acc[i][j][r], x2 = acc[i][j + 2][r];
                    acc[i][j][r]     = x1 * cv - x2 * sv;
                    acc[i][j + 2][r] = x2 * cv + x1 * sv;
                }
            }
        }
    }

    #pragma unroll
    for (int i = 0; i < 2; ++i) {
        #pragma unroll
        for (int r = 0; r < 4; ++r) {
            const int row = m0 + wid * 32 + i * 16 + quad * 4 + r;
            #pragma unroll
            for (int j = 0; j < 4; ++j) {
                const int col = n0 + j * 16 + l16;
                if (BF16OUT)
                    ((ushort*)Cout)[(size_t)row * N + col] = f2bf(acc[i][j][r]);
                else
                    ((float*)Cout)[(size_t)row * N + col] = acc[i][j][r];
            }
        }
    }
}

// ---------------- MFMA flash attention, S^T orientation -------------------
// qkv: [B*T,1536] bf16 (rope + 1/8 q-scale applied). vT: [(b*256+dv)][T].
// y: [B*T,1024] bf16.
// S^T = K@Q^T: each lane holds 16 keys x ONE query (l16) -> softmax m/l are
// lane scalars, cross-quad reduction = 2 shfls. P^T written as 4x b64.
// O^T = V^T@P^T with V A-frags direct from global vT (issued early, hidden
// under QK+softmax). K async-DMA double-buffered with XOR-swizzled source.
#define LPSTR 72
__global__ __launch_bounds__(256) void attn_mfma(
    const ushort* __restrict__ qkv, const ushort* __restrict__ vT,
    ushort* __restrict__ y)
{
    __shared__ __align__(16) short Ks[2][64 * 64];
    __shared__ __align__(16) short Ps[4][16][LPSTR];

    const int tid  = threadIdx.x;
    const int wid  = tid >> 6;
    const int ln   = tid & 63;
    const int l16  = ln & 15;
    const int quad = ln >> 4;

    const int tpb = T_ / 64;
    const int blk = blockIdx.x;
    const int b   = blk / (NH * tpb);
    const int rem = blk % (NH * tpb);
    const int h   = rem / tpb;
    const int tb  = (tpb - 1) - (rem % tpb);     // heavy blocks first
    const int q0  = tb * 64;
    const int kvh = h >> 2;

    const ushort* kbase = qkv + (size_t)(b * T_) * QKVN + 1024 + kvh * HD;
    const ushort* vtb   = vT + (size_t)(b * 256 + kvh * HD) * T_;

    const int r0   = wid * 16;                    // staging rows of this wave
    const int srow = ln >> 3;
    const int sblk = ((ln & 7) ^ srow) * 8;       // XOR-swizzled source col
    const int sl0  = (quad ^ (l16 & 7)) * 8;      // frag slot, d-blocks 0..3
    const int sl1  = sl0 ^ 32;                    // d-blocks 4..7

    // Q B-fragments (pre-scaled by 1/8): B[n=l16][k=quad*8+j]
    short8 qf0, qf1;
    {
        const ushort* qrow = qkv + (size_t)(b * T_ + q0 + wid * 16 + l16) * QKVN + h * HD;
        qf0 = *(const short8*)(qrow + quad * 8);
        qf1 = *(const short8*)(qrow + 32 + quad * 8);
    }

    v4f oacc[4];   // O^T: row d = t*16+quad*4+r, col query = l16
    #pragma unroll
    for (int t = 0; t < 4; ++t) oacc[t] = (v4f){0.f, 0.f, 0.f, 0.f};
    float m = -1e30f, l = 0.f;

    const int nch = q0 / 64 + 1;

    // prologue: stage K chunk 0 into buf 0
    {
        const ushort* kg = kbase + (size_t)(r0 + srow) * QKVN + sblk;
        async16(kg,                    &Ks[0][r0 * 64]);
        async16(kg + (size_t)8 * QKVN, &Ks[0][(r0 + 8) * 64]);
    }

    for (int c = 0; c < nch; ++c) {
        const int key0 = c * 64;
        __syncthreads();   // vmcnt(0): drains chunk-c K DMA (issued last iter)

        // V A-frags for chunk c, direct from global (issued early; the
        // QK MFMAs + softmax below hide the L2 latency)
        short8 vf[4][2];
        #pragma unroll
        for (int t = 0; t < 4; ++t) {
            const ushort* vrow = vtb + (size_t)(t * 16 + l16) * T_ + key0;
            vf[t][0] = *(const short8*)(vrow + quad * 8);
            vf[t][1] = *(const short8*)(vrow + 32 + quad * 8);
        }

        // prefetch K chunk c+1
        if (c + 1 < nch) {
            const int nb = (c + 1) & 1;
            const ushort* kg = kbase + (size_t)(key0 + 64 + r0 + srow) * QKVN + sblk;
            async16(kg,                    &Ks[nb][r0 * 64]);
            async16(kg + (size_t)8 * QKVN, &Ks[nb][(r0 + 8) * 64]);
        }
        const short* Kb = Ks[c & 1];

        // ---- S^T = K @ Q^T (row=key, col=query) ----
        v4f st[4];
        #pragma unroll
        for (int t = 0; t < 4; ++t) {
            short8 k0f = *(const short8*)&Kb[(t * 16 + l16) * 64 + sl0];
            short8 k1f = *(const short8*)&Kb[(t * 16 + l16) * 64 + sl1];
            v4f s = (v4f){0.f, 0.f, 0.f, 0.f};
            s = __builtin_amdgcn_mfma_f32_16x16x32_bf16(k0f, qf0, s, 0, 0, 0);
            s = __builtin_amdgcn_mfma_f32_16x16x32_bf16(k1f, qf1, s, 0, 0, 0);
            st[t] = s;
        }

        // causal mask: only the diagonal chunk (key0 == q0) needs it
        if (c == nch - 1) {
            #pragma unroll
            for (int t = 0; t < 4; ++t)
                #pragma unroll
                for (int r = 0; r < 4; ++r)
                    if (t * 16 + quad * 4 + r > wid * 16 + l16) st[t][r] = -1e30f;
        }

        // ---- online softmax, per-lane query scalar state ----
        float mx = st[0][0];
        #pragma unroll
        for (int t = 0; t < 4; ++t)
            #pragma unroll
            for (int r = 0; r < 4; ++r) mx = fmaxf(mx, st[t][r]);
        mx = fmaxf(mx, __shfl_xor(mx, 16, 64));
        mx = fmaxf(mx, __shfl_xor(mx, 32, 64));
        float mnew  = fmaxf(m, mx);
        float alpha = __expf(m - mnew);
        m = mnew;
        float p[4][4], sum = 0.f;
        #pragma unroll
        for (int t = 0; t < 4; ++t)
            #pragma unroll
            for (int r = 0; r < 4; ++r) {
                p[t][r] = __expf(st[t][r] - mnew);
                sum += p[t][r];
            }
        sum += __shfl_xor(sum, 16, 64);
        sum += __shfl_xor(sum, 32, 64);
        l = l * alpha + sum;

        // write P^T rows: Ps[query=l16][key], 4 consecutive keys -> b64
        #pragma unroll
        for (int t = 0; t < 4; ++t) {
            ushort4 pk;
            pk.x = f2bf(p[t][0]); pk.y = f2bf(p[t][1]);
            pk.z = f2bf(p[t][2]); pk.w = f2bf(p[t][3]);
            *(ushort4*)&Ps[wid][l16][t * 16 + quad * 4] = pk;
        }
        #pragma unroll
        for (int t = 0; t < 4; ++t)
            #pragma unroll
            for (int r = 0; r < 4; ++r) oacc[t][r] *= alpha;

        // wave-private P region: drain only this wave's ds ops
        asm volatile("s_waitcnt lgkmcnt(0)" ::: "memory");
        short8 pa0 = *(const short8*)&Ps[wid][l16][quad * 8];
        short8 pa1 = *(const short8*)&Ps[wid][l16][32 + quad * 8];

        // ---- O^T += V^T @ P^T ----
        #pragma unroll
        for (int t = 0; t < 4; ++t) {
            oacc[t] = __builtin_amdgcn_mfma_f32_16x16x32_bf16(vf[t][0], pa0, oacc[t], 0, 0, 0);
            oacc[t] = __builtin_amdgcn_mfma_f32_16x16x32_bf16(vf[t][1], pa1, oacc[t], 0, 0, 0);
        }
    }

    // epilogue: y[query][h*64+d] = O^T / l ; 4 consecutive d -> ushort4
    const float inv = 1.0f / l;
    ushort* yrow = y + (size_t)(b * T_ + q0 + wid * 16 + l16) * (NH * HD) + h * HD;
    #pragma unroll
    for (int t = 0; t < 4; ++t) {
        ushort4 o;
        o.x = f2bf(oacc[t][0] * inv); o.y = f2bf(oacc[t][1] * inv);
        o.z = f2bf(oacc[t][2] * inv); o.w = f2bf(oacc[t][3] * inv);
        *(ushort4*)(yrow + t * 16 + quad * 4) = o;
    }
}

// ---------------- launcher ----------------
extern "C" void kernel_launch(void* const* d_in, const int* in_sizes, int n_in,
                              void* d_out, int out_size, void* d_ws, size_t ws_size,
                              hipStream_t stream)
{
    const float* x    = (const float*)d_in[0];
    const float* cosT = (const float*)d_in[1];
    const float* sinT = (const float*)d_in[2];
    const float* Wq   = (const float*)d_in[3];
    const float* Wk   = (const float*)d_in[4];
    const float* Wv   = (const float*)d_in[5];
    const float* Wo   = (const float*)d_in[6];
    float* out = (float*)d_out;

    const int M = B_ * T_;  // 4096
    ushort* xb     = (ushort*)d_ws;                       // 4096*1024
    ushort* qkv    = xb  + (size_t)M * C_;                // 4096*1536
    ushort* yb     = qkv + (size_t)M * QKVN;              // 4096*1024
    ushort* WqkvT  = yb  + (size_t)M * C_;                // 1536*1024
    ushort* WoT    = WqkvT + (size_t)QKVN * C_;           // 1024*1024
    ushort* vTbuf  = WoT + (size_t)C_ * C_;               // 2*256*2048

    dim3 blk(256);
    // converts + weight transposes, one launch
    prep<<<640 + (M * C_) / 1024, blk, 0, stream>>>(x, Wq, Wk, Wv, Wo, xb, WqkvT, WoT);
    // fused QKV projection with RoPE + q-scale epilogue (bf16 out)
    gemm_bf16bt<true, true><<<dim3(QKVN / 64, M / 128), blk, 0, stream>>>(
        xb, WqkvT, qkv, cosT, sinT, M, QKVN, C_);
    // v -> vT global transpose
    transpose_v_bf16<<<dim3(T_ / 64, 4, B_), blk, 0, stream>>>(qkv, vTbuf);
    // attention
    attn_mfma<<<B_ * NH * (T_ / 64), blk, 0, stream>>>(qkv, vTbuf, yb);
    // output projection (fp32 out)
    gemm_bf16bt<false, false><<<dim3(C_ / 64, M / 128), blk, 0, stream>>>(
        yb, WoT, out, nullptr, nullptr, M, C_, C_);
}

// Round 7
// 204.565 us; speedup vs baseline: 1.9433x; 1.2869x over previous
//
#include <hip/hip_runtime.h>
#include <hip/hip_bf16.h>
#include <math.h>

#define NH   16
#define NKV  4
#define HD   64
#define B_   2
#define T_   2048
#define C_   1024
#define QKVN 1536   // fused q(1024) | k(256) | v(256)

typedef __attribute__((ext_vector_type(8))) short short8;
typedef __attribute__((ext_vector_type(4))) float v4f;

__device__ inline ushort f2bf(float f) {
    union { float f; uint32_t u; } v; v.f = f;
    uint32_t r = v.u + 0x7fffu + ((v.u >> 16) & 1u);
    return (ushort)(r >> 16);
}

// async global->LDS, 16B per lane; LDS dest wave-uniform base + lane*16
__device__ inline void async16(const void* g, void* l) {
    __builtin_amdgcn_global_load_lds(
        (const __attribute__((address_space(1))) unsigned int*)g,
        (__attribute__((address_space(3))) unsigned int*)l, 16, 0, 0);
}

// ---------------- prep: x f32->bf16 convert + 4 weight transposes ----------
__global__ __launch_bounds__(256) void prep(
    const float* __restrict__ x,
    const float* __restrict__ Wq, const float* __restrict__ Wk,
    const float* __restrict__ Wv, const float* __restrict__ Wo,
    ushort* __restrict__ xb, ushort* __restrict__ WqkvT, ushort* __restrict__ WoT)
{
    const int bx = blockIdx.x;
    const int tid = threadIdx.x;
    if (bx < 640) {
        __shared__ float tile[64][65];
        const int cb = bx >> 4;
        const int kb = bx & 15;
        const float* src; ushort* dst; int N, nb;
        if (cb < 16)      { src = Wq; dst = WqkvT;                     N = 1024; nb = cb; }
        else if (cb < 20) { src = Wk; dst = WqkvT + (size_t)1024 * C_; N = 256;  nb = cb - 16; }
        else if (cb < 24) { src = Wv; dst = WqkvT + (size_t)1280 * C_; N = 256;  nb = cb - 20; }
        else              { src = Wo; dst = WoT;                       N = 1024; nb = cb - 24; }
        const int k0 = kb * 64, n0 = nb * 64;
        #pragma unroll
        for (int it = 0; it < 4; ++it) {
            int r = (tid >> 4) + it * 16;
            int c = (tid & 15) * 4;
            float4 v = *(const float4*)(src + (size_t)(k0 + r) * N + n0 + c);
            tile[r][c] = v.x; tile[r][c + 1] = v.y; tile[r][c + 2] = v.z; tile[r][c + 3] = v.w;
        }
        __syncthreads();
        #pragma unroll
        for (int it = 0; it < 4; ++it) {
            int r = (tid >> 4) + it * 16;
            int c = (tid & 15) * 4;
            ushort4 o;
            o.x = f2bf(tile[c + 0][r]); o.y = f2bf(tile[c + 1][r]);
            o.z = f2bf(tile[c + 2][r]); o.w = f2bf(tile[c + 3][r]);
            *(ushort4*)(dst + (size_t)(n0 + r) * C_ + k0 + c) = o;
        }
    } else {
        int i = ((bx - 640) * 256 + tid) * 4;   // covers 4096*1024 exactly
        float4 v = *(const float4*)(x + i);
        ushort4 o; o.x = f2bf(v.x); o.y = f2bf(v.y); o.z = f2bf(v.z); o.w = f2bf(v.w);
        *(ushort4*)(xb + i) = o;
    }
}

// ---------------- bf16 MFMA GEMM: C[M,N] = A[M,K] @ Bt[N,K]^T --------------
// 128(M)x64(N) tile, BK=32, 4 waves stacked along M (wave: 32m x 64n).
// ROPE path (QKV gemm): n0<1024 -> rope + 1/8 q-scale; 1024<=n0<1280 ->
// rope only (k); n0>=1280 -> v: store DIRECTLY transposed into vT.
template <bool BF16OUT, bool ROPE>
__global__ __launch_bounds__(256) void gemm_bf16bt(
    const ushort* __restrict__ A, const ushort* __restrict__ Bt,
    void* __restrict__ Cout, ushort* __restrict__ vTout,
    const float* __restrict__ cs, const float* __restrict__ sn,
    int M, int N, int K)
{
    __shared__ __align__(16) short As[128 * 32];
    __shared__ __align__(16) short Bs[64 * 32];

    const int tid  = threadIdx.x;
    const int lane = tid & 63;
    const int wid  = tid >> 6;
    const int l16  = lane & 15;
    const int quad = lane >> 4;
    const int m0   = blockIdx.y * 128;
    const int n0   = blockIdx.x * 64;

    v4f acc[2][4];
    #pragma unroll
    for (int i = 0; i < 2; ++i)
        #pragma unroll
        for (int j = 0; j < 4; ++j) acc[i][j] = (v4f){0.f, 0.f, 0.f, 0.f};

    for (int k0 = 0; k0 < K; k0 += 32) {
        __syncthreads();
        {
            const ushort* ag = A + (size_t)(m0 + wid * 32 + (lane >> 2)) * K + k0 + (lane & 3) * 8;
            async16(ag,                  &As[(wid * 32) * 32]);
            async16(ag + (size_t)16 * K, &As[(wid * 32 + 16) * 32]);
            const ushort* bg = Bt + (size_t)(n0 + wid * 16 + (lane >> 2)) * K + k0 + (lane & 3) * 8;
            async16(bg, &Bs[(wid * 16) * 32]);
        }
        __syncthreads();

        short8 af[2], bf[4];
        #pragma unroll
        for (int i = 0; i < 2; ++i)
            af[i] = *(const short8*)&As[(wid * 32 + i * 16 + l16) * 32 + quad * 8];
        #pragma unroll
        for (int j = 0; j < 4; ++j)
            bf[j] = *(const short8*)&Bs[(j * 16 + l16) * 32 + quad * 8];
        #pragma unroll
        for (int i = 0; i < 2; ++i)
            #pragma unroll
            for (int j = 0; j < 4; ++j)
                acc[i][j] = __builtin_amdgcn_mfma_f32_16x16x32_bf16(af[i], bf[j], acc[i][j], 0, 0, 0);
    }

    if (ROPE && n0 >= 1280) {
        // v tile: store transposed to vT[(b*256 + (col-1280))][t], ushort4 along t
        #pragma unroll
        for (int i = 0; i < 2; ++i) {
            const int row = m0 + wid * 32 + i * 16 + quad * 4;   // 4 consecutive t
            const int bb  = row >> 11;                            // row / T_
            const int t   = row & (T_ - 1);
            #pragma unroll
            for (int j = 0; j < 4; ++j) {
                const int vc = n0 - 1280 + j * 16 + l16;
                ushort4 o;
                o.x = f2bf(acc[i][j][0]); o.y = f2bf(acc[i][j][1]);
                o.z = f2bf(acc[i][j][2]); o.w = f2bf(acc[i][j][3]);
                *(ushort4*)(vTout + (size_t)(bb * 256 + vc) * T_ + t) = o;
            }
        }
        return;
    }

    if (ROPE) {
        const float qs = (n0 < 1024) ? 0.125f : 1.0f;   // fold attn scale into q
        #pragma unroll
        for (int i = 0; i < 2; ++i) {
            #pragma unroll
            for (int r = 0; r < 4; ++r) {
                const int row = m0 + wid * 32 + i * 16 + quad * 4 + r;
                const int t = row & (T_ - 1);
                #pragma unroll
                for (int j = 0; j < 2; ++j) {
                    const int d = j * 16 + l16;
                    float cv = cs[t * 32 + d] * qs, sv = sn[t * 32 + d] * qs;
                    float x1 = acc[i][j][r], x2 = acc[i][j + 2][r];
                    acc[i][j][r]     = x1 * cv - x2 * sv;
                    acc[i][j + 2][r] = x2 * cv + x1 * sv;
                }
            }
        }
    }

    #pragma unroll
    for (int i = 0; i < 2; ++i) {
        #pragma unroll
        for (int r = 0; r < 4; ++r) {
            const int row = m0 + wid * 32 + i * 16 + quad * 4 + r;
            #pragma unroll
            for (int j = 0; j < 4; ++j) {
                const int col = n0 + j * 16 + l16;
                if (BF16OUT)
                    ((ushort*)Cout)[(size_t)row * N + col] = f2bf(acc[i][j][r]);
                else
                    ((float*)Cout)[(size_t)row * N + col] = acc[i][j][r];
            }
        }
    }
}

// ---------------- MFMA flash attention, S^T + XCD swizzle + paired tiles --
// Grid = 512. blockIdx&7 -> (b,kvh) so each XCD's K/V slice (256KB+256KB)
// stays L2-resident (the R5/R6 135us plateau was L2 thrash: 6MB K+V working
// set > 4MB per-XCD L2 -> every chunk stalled on L3 latency).
// Each block does two q-tiles (31-p, p): uniform 33 chunks -> no tail.
#define LPSTR 72
__global__ __launch_bounds__(256) void attn_mfma(
    const ushort* __restrict__ qkv, const ushort* __restrict__ vT,
    ushort* __restrict__ y)
{
    __shared__ __align__(16) short Ks[2][64 * 64];
    __shared__ __align__(16) short Ps[4][16][LPSTR];

    const int tid  = threadIdx.x;
    const int wid  = tid >> 6;
    const int ln   = tid & 63;
    const int l16  = ln & 15;
    const int quad = ln >> 4;

    const int bi   = blockIdx.x;          // 0..511
    const int xcd  = bi & 7;
    const int b    = xcd >> 2;
    const int kvh  = xcd & 3;
    const int jj   = bi >> 3;             // 0..63
    const int h    = kvh * 4 + (jj & 3);
    const int pr   = jj >> 2;             // 0..15

    const ushort* kbase = qkv + (size_t)(b * T_) * QKVN + 1024 + kvh * HD;
    const ushort* vtb   = vT + (size_t)(b * 256 + kvh * HD) * T_;

    const int r0   = wid * 16;                    // staging rows of this wave
    const int srow = ln >> 3;
    const int sblk = ((ln & 7) ^ srow) * 8;       // XOR-swizzled source col
    const int sl0  = (quad ^ (l16 & 7)) * 8;      // frag slot, d-blocks 0..3
    const int sl1  = sl0 ^ 32;                    // d-blocks 4..7

    #pragma unroll 1
    for (int pass = 0; pass < 2; ++pass) {
        const int tb = pass ? pr : (31 - pr);     // heavy tile first
        const int q0 = tb * 64;
        const int nch = tb + 1;

        // Q B-fragments (pre-scaled by 1/8): B[n=l16][k=quad*8+j]
        short8 qf0, qf1;
        {
            const ushort* qrow = qkv + (size_t)(b * T_ + q0 + wid * 16 + l16) * QKVN + h * HD;
            qf0 = *(const short8*)(qrow + quad * 8);
            qf1 = *(const short8*)(qrow + 32 + quad * 8);
        }

        v4f oacc[4];
        #pragma unroll
        for (int t = 0; t < 4; ++t) oacc[t] = (v4f){0.f, 0.f, 0.f, 0.f};
        float m = -1e30f, l = 0.f;

        if (pass) __syncthreads();   // protect Ks reuse across passes

        // prologue: stage K chunk 0 into buf 0
        {
            const ushort* kg = kbase + (size_t)(r0 + srow) * QKVN + sblk;
            async16(kg,                    &Ks[0][r0 * 64]);
            async16(kg + (size_t)8 * QKVN, &Ks[0][(r0 + 8) * 64]);
        }

        for (int c = 0; c < nch; ++c) {
            const int key0 = c * 64;
            __syncthreads();   // vmcnt(0): drains chunk-c K DMA

            // V A-frags for chunk c, direct from global (L2-hit after swizzle;
            // issued early, consumed at chunk end)
            short8 vf[4][2];
            #pragma unroll
            for (int t = 0; t < 4; ++t) {
                const ushort* vrow = vtb + (size_t)(t * 16 + l16) * T_ + key0;
                vf[t][0] = *(const short8*)(vrow + quad * 8);
                vf[t][1] = *(const short8*)(vrow + 32 + quad * 8);
            }

            // prefetch K chunk c+1
            if (c + 1 < nch) {
                const int nb = (c + 1) & 1;
                const ushort* kg = kbase + (size_t)(key0 + 64 + r0 + srow) * QKVN + sblk;
                async16(kg,                    &Ks[nb][r0 * 64]);
                async16(kg + (size_t)8 * QKVN, &Ks[nb][(r0 + 8) * 64]);
            }
            const short* Kb = Ks[c & 1];

            // ---- S^T = K @ Q^T (row=key, col=query) ----
            v4f st[4];
            #pragma unroll
            for (int t = 0; t < 4; ++t) {
                short8 k0f = *(const short8*)&Kb[(t * 16 + l16) * 64 + sl0];
                short8 k1f = *(const short8*)&Kb[(t * 16 + l16) * 64 + sl1];
                v4f s = (v4f){0.f, 0.f, 0.f, 0.f};
                s = __builtin_amdgcn_mfma_f32_16x16x32_bf16(k0f, qf0, s, 0, 0, 0);
                s = __builtin_amdgcn_mfma_f32_16x16x32_bf16(k1f, qf1, s, 0, 0, 0);
                st[t] = s;
            }

            // causal mask: only the diagonal chunk (key0 == q0)
            if (c == nch - 1) {
                #pragma unroll
                for (int t = 0; t < 4; ++t)
                    #pragma unroll
                    for (int r = 0; r < 4; ++r)
                        if (t * 16 + quad * 4 + r > wid * 16 + l16) st[t][r] = -1e30f;
            }

            // ---- online softmax, per-lane query scalar state ----
            float mx = st[0][0];
            #pragma unroll
            for (int t = 0; t < 4; ++t)
                #pragma unroll
                for (int r = 0; r < 4; ++r) mx = fmaxf(mx, st[t][r]);
            mx = fmaxf(mx, __shfl_xor(mx, 16, 64));
            mx = fmaxf(mx, __shfl_xor(mx, 32, 64));
            float mnew  = fmaxf(m, mx);
            float alpha = __expf(m - mnew);
            m = mnew;
            float p[4][4], sum = 0.f;
            #pragma unroll
            for (int t = 0; t < 4; ++t)
                #pragma unroll
                for (int r = 0; r < 4; ++r) {
                    p[t][r] = __expf(st[t][r] - mnew);
                    sum += p[t][r];
                }
            sum += __shfl_xor(sum, 16, 64);
            sum += __shfl_xor(sum, 32, 64);
            l = l * alpha + sum;

            // write P^T rows: Ps[query=l16][key], 4 consecutive keys -> b64
            #pragma unroll
            for (int t = 0; t < 4; ++t) {
                ushort4 pk;
                pk.x = f2bf(p[t][0]); pk.y = f2bf(p[t][1]);
                pk.z = f2bf(p[t][2]); pk.w = f2bf(p[t][3]);
                *(ushort4*)&Ps[wid][l16][t * 16 + quad * 4] = pk;
            }
            #pragma unroll
            for (int t = 0; t < 4; ++t)
                #pragma unroll
                for (int r = 0; r < 4; ++r) oacc[t][r] *= alpha;

            // wave-private P region: drain only this wave's ds ops
            asm volatile("s_waitcnt lgkmcnt(0)" ::: "memory");
            short8 pa0 = *(const short8*)&Ps[wid][l16][quad * 8];
            short8 pa1 = *(const short8*)&Ps[wid][l16][32 + quad * 8];

            // ---- O^T += V^T @ P^T ----
            #pragma unroll
            for (int t = 0; t < 4; ++t) {
                oacc[t] = __builtin_amdgcn_mfma_f32_16x16x32_bf16(vf[t][0], pa0, oacc[t], 0, 0, 0);
                oacc[t] = __builtin_amdgcn_mfma_f32_16x16x32_bf16(vf[t][1], pa1, oacc[t], 0, 0, 0);
            }
        }

        // epilogue: y[query][h*64+d] = O^T / l
        const float inv = 1.0f / l;
        ushort* yrow = y + (size_t)(b * T_ + q0 + wid * 16 + l16) * (NH * HD) + h * HD;
        #pragma unroll
        for (int t = 0; t < 4; ++t) {
            ushort4 o;
            o.x = f2bf(oacc[t][0] * inv); o.y = f2bf(oacc[t][1] * inv);
            o.z = f2bf(oacc[t][2] * inv); o.w = f2bf(oacc[t][3] * inv);
            *(ushort4*)(yrow + t * 16 + quad * 4) = o;
        }
    }
}

// ---------------- launcher ----------------
extern "C" void kernel_launch(void* const* d_in, const int* in_sizes, int n_in,
                              void* d_out, int out_size, void* d_ws, size_t ws_size,
                              hipStream_t stream)
{
    const float* x    = (const float*)d_in[0];
    const float* cosT = (const float*)d_in[1];
    const float* sinT = (const float*)d_in[2];
    const float* Wq   = (const float*)d_in[3];
    const float* Wk   = (const float*)d_in[4];
    const float* Wv   = (const float*)d_in[5];
    const float* Wo   = (const float*)d_in[6];
    float* out = (float*)d_out;

    const int M = B_ * T_;  // 4096
    ushort* xb     = (ushort*)d_ws;                       // 4096*1024
    ushort* qkv    = xb  + (size_t)M * C_;                // 4096*1536
    ushort* yb     = qkv + (size_t)M * QKVN;              // 4096*1024
    ushort* WqkvT  = yb  + (size_t)M * C_;                // 1536*1024
    ushort* WoT    = WqkvT + (size_t)QKVN * C_;           // 1024*1024
    ushort* vTbuf  = WoT + (size_t)C_ * C_;               // 2*256*2048

    dim3 blk(256);
    // converts + weight transposes, one launch
    prep<<<640 + (M * C_) / 1024, blk, 0, stream>>>(x, Wq, Wk, Wv, Wo, xb, WqkvT, WoT);
    // fused QKV projection: rope + q-scale epilogue, v written straight to vT
    gemm_bf16bt<true, true><<<dim3(QKVN / 64, M / 128), blk, 0, stream>>>(
        xb, WqkvT, qkv, vTbuf, cosT, sinT, M, QKVN, C_);
    // attention (XCD-swizzled, paired tiles)
    attn_mfma<<<512, blk, 0, stream>>>(qkv, vTbuf, yb);
    // output projection (fp32 out)
    gemm_bf16bt<false, false><<<dim3(C_ / 64, M / 128), blk, 0, stream>>>(
        yb, WoT, out, nullptr, nullptr, nullptr, M, C_, C_);
}